// Round 1
// baseline (88.828 us; speedup 1.0000x reference)
//
#include <hip/hip_runtime.h>

#define CCH   64
#define HH    64
#define WW    64
#define NPIX  4096          // H*W
#define NTYPES 216
#define KKW   9             // 3x3
#define CKK   576           // C*K*K
#define ROWLEN 577          // CKK + 1 (bias)
#define NP    16            // pixels per chunk
#define SLOTS 3             // chunk slots per bucket

// ---------------- K1: grouped 3x3 conv + bias + relu -> h ----------------
__global__ __launch_bounds__(256) void body1_kernel(
        const float* __restrict__ x, const float* __restrict__ w1,
        const float* __restrict__ b1, float* __restrict__ h) {
    int flat = blockIdx.x * 256 + threadIdx.x;   // c*4096 + y*64 + xw
    int xw = flat & 63;
    int y  = (flat >> 6) & 63;
    int c  = flat >> 12;
    int g  = c >> 4;
    const float* wrow = w1 + c * (16 * 9);
    float acc = b1[c];
    #pragma unroll
    for (int ci = 0; ci < 16; ++ci) {
        const float* xp = x + (g * 16 + ci) * 4096;
        #pragma unroll
        for (int dy = 0; dy < 3; ++dy) {
            int yy = y + dy - 1;
            if (yy < 0 || yy > 63) continue;
            #pragma unroll
            for (int dx = 0; dx < 3; ++dx) {
                int xx = xw + dx - 1;
                if (xx < 0 || xx > 63) continue;
                acc = fmaf(xp[yy * 64 + xx], wrow[ci * 9 + dy * 3 + dx], acc);
            }
        }
    }
    h[flat] = fmaxf(acc, 0.f);
}

// ---------------- K2: counting sort of pixels by bucket ----------------
__global__ __launch_bounds__(256) void sort_kernel(
        const int* __restrict__ buckets, int* __restrict__ offsets,
        int* __restrict__ sorted) {
    __shared__ int cnt[NTYPES];
    __shared__ int off[NTYPES + 1];
    int tid = threadIdx.x;
    for (int i = tid; i < NTYPES; i += 256) cnt[i] = 0;
    __syncthreads();
    for (int i = tid; i < NPIX; i += 256) atomicAdd(&cnt[buckets[i]], 1);
    __syncthreads();
    if (tid == 0) {
        int s = 0;
        for (int t = 0; t < NTYPES; ++t) { off[t] = s; s += cnt[t]; }
        off[NTYPES] = s;
    }
    __syncthreads();
    for (int i = tid; i <= NTYPES; i += 256) offsets[i] = off[i];
    for (int i = tid; i < NTYPES; i += 256) cnt[i] = off[i];
    __syncthreads();
    for (int i = tid; i < NPIX; i += 256) {
        int b = buckets[i];
        int pos = atomicAdd(&cnt[b], 1);
        sorted[pos] = i;
    }
}

// ------- K3: per-bucket dynamic conv + relu + 1x1 + bias + residual + relu -------
__global__ __launch_bounds__(256) void dyn_kernel(
        const float* __restrict__ h, const float* __restrict__ emb,
        const float* __restrict__ w2, const float* __restrict__ b2,
        const float* __restrict__ x, const int* __restrict__ offsets,
        const int* __restrict__ sorted, float* __restrict__ out) {

    __shared__ float P[CKK][NP];        // 36 KB patches
    __shared__ float w2s[64 * 64];      // 16 KB
    __shared__ float D[64][NP + 1];     // +1 pad: avoid 4-way bank conflict
    __shared__ int   pix[NP];

    int t     = blockIdx.x;
    int slot  = blockIdx.y;
    int start = offsets[t];
    int n     = offsets[t + 1] - start;
    if (n <= 0) return;
    int tid = threadIdx.x;

    for (int i = tid; i < 64 * 64; i += 256) w2s[i] = w2[i];

    const float* Wt = emb + (size_t)t * (64 * ROWLEN);

    int p  = tid & (NP - 1);
    int ob = (tid >> 4) * 4;            // 0,4,...,60

    for (int base = slot * NP; base < n; base += SLOTS * NP) {
        int np = min(NP, n - base);
        __syncthreads();                 // protect P/pix reuse
        if (tid < NP) pix[tid] = (tid < np) ? sorted[start + base + tid] : -1;
        __syncthreads();

        // stage patches P[c9][p] from h (zero-pad OOB / invalid p)
        for (int i = tid; i < CKK * NP; i += 256) {
            int pp = i & (NP - 1);
            int c9 = i >> 4;             // i / NP
            float v = 0.f;
            int pi = pix[pp];
            if (pi >= 0) {
                int py = pi >> 6, px = pi & 63;
                int ci = c9 / 9, r9 = c9 - ci * 9;
                int dy = r9 / 3, dx = r9 - dy * 3;
                int yy = py + dy - 1, xx = px + dx - 1;
                if (yy >= 0 && yy < 64 && xx >= 0 && xx < 64)
                    v = h[ci * 4096 + yy * 64 + xx];
            }
            P[c9][pp] = v;
        }
        __syncthreads();

        // dynamic conv: 4 output channels per thread, 576-long dot products
        const float* w0 = Wt + (size_t)(ob + 0) * ROWLEN;
        const float* w1r = Wt + (size_t)(ob + 1) * ROWLEN;
        const float* w2r = Wt + (size_t)(ob + 2) * ROWLEN;
        const float* w3 = Wt + (size_t)(ob + 3) * ROWLEN;
        float a0 = w0[CKK], a1 = w1r[CKK], a2 = w2r[CKK], a3 = w3[CKK]; // per-pixel bias
        #pragma unroll 8
        for (int c9 = 0; c9 < CKK; ++c9) {
            float pv = P[c9][p];
            a0 = fmaf(pv, w0[c9], a0);
            a1 = fmaf(pv, w1r[c9], a1);
            a2 = fmaf(pv, w2r[c9], a2);
            a3 = fmaf(pv, w3[c9], a3);
        }
        D[ob + 0][p] = fmaxf(a0, 0.f);
        D[ob + 1][p] = fmaxf(a1, 0.f);
        D[ob + 2][p] = fmaxf(a2, 0.f);
        D[ob + 3][p] = fmaxf(a3, 0.f);
        __syncthreads();

        // 1x1 conv + bias + residual + relu
        int pi = pix[p];
        if (pi >= 0) {
            float r0 = b2[ob + 0], r1 = b2[ob + 1], r2 = b2[ob + 2], r3 = b2[ob + 3];
            #pragma unroll 8
            for (int c = 0; c < 64; ++c) {
                float dv = D[c][p];
                r0 = fmaf(dv, w2s[(ob + 0) * 64 + c], r0);
                r1 = fmaf(dv, w2s[(ob + 1) * 64 + c], r1);
                r2 = fmaf(dv, w2s[(ob + 2) * 64 + c], r2);
                r3 = fmaf(dv, w2s[(ob + 3) * 64 + c], r3);
            }
            out[(ob + 0) * 4096 + pi] = fmaxf(r0 + x[(ob + 0) * 4096 + pi], 0.f);
            out[(ob + 1) * 4096 + pi] = fmaxf(r1 + x[(ob + 1) * 4096 + pi], 0.f);
            out[(ob + 2) * 4096 + pi] = fmaxf(r2 + x[(ob + 2) * 4096 + pi], 0.f);
            out[(ob + 3) * 4096 + pi] = fmaxf(r3 + x[(ob + 3) * 4096 + pi], 0.f);
        }
    }
}

extern "C" void kernel_launch(void* const* d_in, const int* in_sizes, int n_in,
                              void* d_out, int out_size, void* d_ws, size_t ws_size,
                              hipStream_t stream) {
    const float* x       = (const float*)d_in[0];
    const int*   buckets = (const int*)d_in[1];
    const float* w1      = (const float*)d_in[2];
    const float* b1      = (const float*)d_in[3];
    const float* emb     = (const float*)d_in[4];
    const float* w2      = (const float*)d_in[5];
    const float* b2      = (const float*)d_in[6];
    float* out = (float*)d_out;

    char* ws = (char*)d_ws;
    float* h       = (float*)ws;                       // 1 MB
    int*   offsets = (int*)(ws + (1 << 20));           // 217 ints (pad 1 KB)
    int*   sorted  = (int*)(ws + (1 << 20) + 1024);    // 4096 ints

    body1_kernel<<<1024, 256, 0, stream>>>(x, w1, b1, h);
    sort_kernel<<<1, 256, 0, stream>>>(buckets, offsets, sorted);
    dim3 g3(NTYPES, SLOTS);
    dyn_kernel<<<g3, 256, 0, stream>>>(h, emb, w2, b2, x, offsets, sorted, out);
}

// Round 2
// 54.942 us; speedup vs baseline: 1.6168x; 1.6168x over previous
//
#include <hip/hip_runtime.h>

#define NTYPES 216
#define NPIX   4096
#define KD     576      // C*3*3
#define ROWLEN 577      // KD + bias
#define NCHUNK 9        // KD / 64
#define NPC    32       // pixels per chunk

typedef __attribute__((ext_vector_type(8))) short   short8;
typedef __attribute__((ext_vector_type(4))) float   f32x4;
typedef __attribute__((ext_vector_type(8))) unsigned short u16x8;
typedef __attribute__((ext_vector_type(4))) unsigned short u16x4;

static __device__ __forceinline__ unsigned short f2bf(float f) {
    unsigned u = __builtin_bit_cast(unsigned, f);
    unsigned r = (u + 0x7FFFu + ((u >> 16) & 1u)) >> 16;  // round-to-nearest-even
    return (unsigned short)r;
}

// ---------------- K1: grouped 3x3 conv + bias + relu -> h ----------------
__global__ __launch_bounds__(256) void body1_kernel(
        const float* __restrict__ x, const float* __restrict__ w1,
        const float* __restrict__ b1, float* __restrict__ h) {
    int flat = blockIdx.x * 256 + threadIdx.x;   // c*4096 + y*64 + xw
    int xw = flat & 63;
    int y  = (flat >> 6) & 63;
    int c  = flat >> 12;
    int g  = c >> 4;
    const float* wrow = w1 + c * (16 * 9);
    float acc = b1[c];
    #pragma unroll
    for (int ci = 0; ci < 16; ++ci) {
        const float* xp = x + (g * 16 + ci) * 4096;
        #pragma unroll
        for (int dy = 0; dy < 3; ++dy) {
            int yy = y + dy - 1;
            if (yy < 0 || yy > 63) continue;
            #pragma unroll
            for (int dx = 0; dx < 3; ++dx) {
                int xx = xw + dx - 1;
                if (xx < 0 || xx > 63) continue;
                acc = fmaf(xp[yy * 64 + xx], wrow[ci * 9 + dy * 3 + dx], acc);
            }
        }
    }
    h[flat] = fmaxf(acc, 0.f);
}

// ---------------- K2: counting sort of pixels by bucket ----------------
__global__ __launch_bounds__(256) void sort_kernel(
        const int* __restrict__ buckets, int* __restrict__ offsets,
        int* __restrict__ sorted) {
    __shared__ int cnt[NTYPES];
    __shared__ int off[NTYPES + 1];
    int tid = threadIdx.x;
    for (int i = tid; i < NTYPES; i += 256) cnt[i] = 0;
    __syncthreads();
    for (int i = tid; i < NPIX; i += 256) atomicAdd(&cnt[buckets[i]], 1);
    __syncthreads();
    if (tid == 0) {
        int s = 0;
        for (int t = 0; t < NTYPES; ++t) { off[t] = s; s += cnt[t]; }
        off[NTYPES] = s;
    }
    __syncthreads();
    for (int i = tid; i <= NTYPES; i += 256) offsets[i] = off[i];
    for (int i = tid; i < NTYPES; i += 256) cnt[i] = off[i];
    __syncthreads();
    for (int i = tid; i < NPIX; i += 256) {
        int b = buckets[i];
        int pos = atomicAdd(&cnt[b], 1);
        sorted[pos] = i;
    }
}

// ------- K3: per-bucket MFMA GEMM: dynconv + bias + relu + 1x1 + residual + relu -------
__global__ __launch_bounds__(512) void dyn_kernel(
        const float* __restrict__ h, const float* __restrict__ emb,
        const float* __restrict__ w2, const float* __restrict__ b2,
        const float* __restrict__ x, const int* __restrict__ offsets,
        const int* __restrict__ sorted, float* __restrict__ out) {

    // strides padded so every b128 access is 16B-aligned and ~2-way-banked
    __shared__ float          Wl[2][64 * 68];   // 34816 B  (f32 filter chunk, dbuf)
    __shared__ unsigned short Pl[2][NPC * 72];  //  9216 B  (bf16 patch chunk, dbuf)
    __shared__ unsigned short Dl[NPC * 72];     //  4608 B  (bf16 intermediate D)
    __shared__ unsigned short w2l[64 * 72];     //  9216 B  (bf16 1x1 weights)
    __shared__ int pixs[NPC];

    int t = blockIdx.x;
    int start = offsets[t];
    int n = offsets[t + 1] - start;
    if (n <= 0) return;

    int tid  = threadIdx.x;
    int lane = tid & 63;
    int wv   = tid >> 6;       // 0..7
    int m    = wv & 3;         // M-tile (16 out channels)
    int ph   = wv >> 2;        // pixel half (16 pixels)
    int ra   = lane & 15;
    int kg   = lane >> 4;      // k-octet group 0..3

    const float* Wt = emb + (size_t)t * (64 * ROWLEN);

    // stage w2 -> bf16 LDS (once)
    {
        int o = tid >> 3, i8 = (tid & 7) * 8;
        const float* src = w2 + o * 64 + i8;
        u16x8 v;
        #pragma unroll
        for (int j = 0; j < 8; ++j) v[j] = f2bf(src[j]);
        *(u16x8*)&w2l[o * 72 + i8] = v;
    }

    // staging roles
    int srow = tid >> 3;           // W stage: row 0..63
    int skk  = (tid & 7) * 8;      // W stage: k offset within chunk
    int pp   = tid >> 4;           // P stage: pixel 0..31
    int pk0  = (tid & 15) * 4;     // P stage: k-local 0..60

    for (int base = 0; base < n; base += NPC) {
        __syncthreads();   // protect pixs/Pl/Dl from previous iteration
        if (tid < NPC) pixs[tid] = (base + tid < n) ? sorted[start + base + tid] : -1;
        __syncthreads();

        // ---- prologue: stage chunk 0 into buf 0 ----
        {
            const float* src = Wt + srow * ROWLEN + skk;
            float r[8];
            #pragma unroll
            for (int j = 0; j < 8; ++j) r[j] = src[j];
            float* dst = &Wl[0][srow * 68 + skk];
            *(f32x4*)dst       = (f32x4){r[0], r[1], r[2], r[3]};
            *(f32x4*)(dst + 4) = (f32x4){r[4], r[5], r[6], r[7]};

            int pixel = pixs[pp];
            int py = pixel >> 6, px = pixel & 63;
            u16x4 pv;
            #pragma unroll
            for (int j = 0; j < 4; ++j) {
                int k = pk0 + j;
                int c = k / 9, r9 = k - c * 9;
                int dy = r9 / 3, dx = r9 - dy * 3;
                float val = 0.f;
                if (pixel >= 0) {
                    int yy = py + dy - 1, xx = px + dx - 1;
                    if (yy >= 0 && yy < 64 && xx >= 0 && xx < 64)
                        val = h[c * 4096 + yy * 64 + xx];
                }
                pv[j] = f2bf(val);
            }
            *(u16x4*)&Pl[0][pp * 72 + pk0] = pv;
        }
        __syncthreads();

        f32x4 acc = {0.f, 0.f, 0.f, 0.f};
        int buf = 0;

        for (int ck = 0; ck < NCHUNK; ++ck) {
            bool havenext = (ck + 1 < NCHUNK);
            float wr[8];
            u16x4 pv;
            if (havenext) {
                // issue next-chunk global loads EARLY (T14 split)
                int k0 = (ck + 1) * 64;
                const float* src = Wt + srow * ROWLEN + k0 + skk;
                #pragma unroll
                for (int j = 0; j < 8; ++j) wr[j] = src[j];

                int pixel = pixs[pp];
                int py = pixel >> 6, px = pixel & 63;
                #pragma unroll
                for (int j = 0; j < 4; ++j) {
                    int k = k0 + pk0 + j;
                    int c = k / 9, r9 = k - c * 9;
                    int dy = r9 / 3, dx = r9 - dy * 3;
                    float val = 0.f;
                    if (pixel >= 0) {
                        int yy = py + dy - 1, xx = px + dx - 1;
                        if (yy >= 0 && yy < 64 && xx >= 0 && xx < 64)
                            val = h[c * 4096 + yy * 64 + xx];
                    }
                    pv[j] = f2bf(val);
                }
            }

            // compute current chunk: 2 k-steps of 32
            #pragma unroll
            for (int ks = 0; ks < 2; ++ks) {
                const float* wp = &Wl[buf][(m * 16 + ra) * 68 + ks * 32 + kg * 8];
                f32x4 w0 = *(const f32x4*)wp;
                f32x4 w1 = *(const f32x4*)(wp + 4);
                short8 av;
                av[0] = (short)f2bf(w0[0]); av[1] = (short)f2bf(w0[1]);
                av[2] = (short)f2bf(w0[2]); av[3] = (short)f2bf(w0[3]);
                av[4] = (short)f2bf(w1[0]); av[5] = (short)f2bf(w1[1]);
                av[6] = (short)f2bf(w1[2]); av[7] = (short)f2bf(w1[3]);
                u16x8 bv = *(const u16x8*)&Pl[buf][(ph * 16 + ra) * 72 + ks * 32 + kg * 8];
                acc = __builtin_amdgcn_mfma_f32_16x16x32_bf16(
                          av, __builtin_bit_cast(short8, bv), acc, 0, 0, 0);
            }

            if (havenext) {
                // write next chunk to the other buffer
                float* dst = &Wl[buf ^ 1][srow * 68 + skk];
                *(f32x4*)dst       = (f32x4){wr[0], wr[1], wr[2], wr[3]};
                *(f32x4*)(dst + 4) = (f32x4){wr[4], wr[5], wr[6], wr[7]};
                *(u16x4*)&Pl[buf ^ 1][pp * 72 + pk0] = pv;
            }
            __syncthreads();
            buf ^= 1;
        }

        // ---- bias + relu -> Dl (bf16) ----
        {
            int och0 = m * 16 + kg * 4;
            int pi   = ph * 16 + ra;
            u16x4 dv;
            #pragma unroll
            for (int j = 0; j < 4; ++j) {
                float bias = Wt[(och0 + j) * ROWLEN + KD];
                float v = fmaxf(acc[j] + bias, 0.f);
                dv[j] = f2bf(v);
            }
            *(u16x4*)&Dl[pi * 72 + och0] = dv;
        }
        __syncthreads();

        // ---- GEMM2: 1x1 conv (K=64, 2 k-steps) ----
        f32x4 acc2 = {0.f, 0.f, 0.f, 0.f};
        #pragma unroll
        for (int ks = 0; ks < 2; ++ks) {
            u16x8 a2  = *(const u16x8*)&w2l[(m * 16 + ra) * 72 + ks * 32 + kg * 8];
            u16x8 b2v = *(const u16x8*)&Dl[(ph * 16 + ra) * 72 + ks * 32 + kg * 8];
            acc2 = __builtin_amdgcn_mfma_f32_16x16x32_bf16(
                       __builtin_bit_cast(short8, a2),
                       __builtin_bit_cast(short8, b2v), acc2, 0, 0, 0);
        }

        // ---- epilogue: + b2 + residual, relu, store ----
        {
            int och0 = m * 16 + kg * 4;
            int pi   = ph * 16 + ra;
            int pixel = pixs[pi];
            if (pixel >= 0) {
                #pragma unroll
                for (int j = 0; j < 4; ++j) {
                    int o = och0 + j;
                    float v = acc2[j] + b2[o] + x[o * 4096 + pixel];
                    out[o * 4096 + pixel] = fmaxf(v, 0.f);
                }
            }
        }
    }
}

extern "C" void kernel_launch(void* const* d_in, const int* in_sizes, int n_in,
                              void* d_out, int out_size, void* d_ws, size_t ws_size,
                              hipStream_t stream) {
    const float* x       = (const float*)d_in[0];
    const int*   buckets = (const int*)d_in[1];
    const float* w1      = (const float*)d_in[2];
    const float* b1      = (const float*)d_in[3];
    const float* emb     = (const float*)d_in[4];
    const float* w2      = (const float*)d_in[5];
    const float* b2      = (const float*)d_in[6];
    float* out = (float*)d_out;

    char* ws = (char*)d_ws;
    float* h       = (float*)ws;                       // 1 MB
    int*   offsets = (int*)(ws + (1 << 20));           // 217 ints
    int*   sorted  = (int*)(ws + (1 << 20) + 1024);    // 4096 ints

    body1_kernel<<<1024, 256, 0, stream>>>(x, w1, b1, h);
    sort_kernel<<<1, 256, 0, stream>>>(buckets, offsets, sorted);
    dyn_kernel<<<NTYPES, 512, 0, stream>>>(h, emb, w2, b2, x, offsets, sorted, out);
}

// Round 4
// 42.298 us; speedup vs baseline: 2.1000x; 1.2989x over previous
//
#include <hip/hip_runtime.h>

#define NTYPES 216
#define NPIX   4096
#define KD     576      // C*3*3
#define ROWLEN 577      // KD + bias
#define NPC    32       // pixels per block-iteration
#define PSTR   640      // u16 elements per pixel row in Pl (576 data + 64 shift pad)

typedef __attribute__((ext_vector_type(8))) short short8;
typedef __attribute__((ext_vector_type(4))) float f32x4;
typedef __attribute__((ext_vector_type(8))) unsigned short u16x8;
typedef __attribute__((ext_vector_type(4))) unsigned short u16x4;

static __device__ __forceinline__ unsigned short f2bf(float f) {
    unsigned u = __builtin_bit_cast(unsigned, f);
    unsigned r = (u + 0x7FFFu + ((u >> 16) & 1u)) >> 16;  // RNE
    return (unsigned short)r;
}

// ---------- Kernel A: blocks 0..255 grouped conv (vectorized); block 256 sort ----------
__global__ __launch_bounds__(256) void body1_sort_kernel(
        const float* __restrict__ x, const float* __restrict__ w1,
        const float* __restrict__ b1, const int* __restrict__ buckets,
        float* __restrict__ h, int* __restrict__ offsets, int* __restrict__ sorted) {
    int tid = threadIdx.x;
    if (blockIdx.x == 256) {
        __shared__ int cnt[NTYPES];
        __shared__ int off[NTYPES + 1];
        for (int i = tid; i < NTYPES; i += 256) cnt[i] = 0;
        __syncthreads();
        for (int i = tid; i < NPIX; i += 256) atomicAdd(&cnt[buckets[i]], 1);
        __syncthreads();
        if (tid == 0) {
            int s = 0;
            for (int t = 0; t < NTYPES; ++t) { off[t] = s; s += cnt[t]; }
            off[NTYPES] = s;
        }
        __syncthreads();
        for (int i = tid; i <= NTYPES; i += 256) offsets[i] = off[i];
        for (int i = tid; i < NTYPES; i += 256) cnt[i] = off[i];
        __syncthreads();
        for (int i = tid; i < NPIX; i += 256) {
            int b = buckets[i];
            sorted[atomicAdd(&cnt[b], 1)] = i;
        }
        return;
    }
    int flat = blockIdx.x * 256 + tid;   // c(6) | y(6) | x4(4)
    int x4 = flat & 15;
    int y  = (flat >> 4) & 63;
    int c  = flat >> 10;                  // block-uniform
    int g  = c >> 4;
    const float* wrow = w1 + c * 144;
    float o0, o1, o2, o3;
    o0 = o1 = o2 = o3 = b1[c];
    #pragma unroll
    for (int ci = 0; ci < 16; ++ci) {
        const float* xp = x + (g * 16 + ci) * 4096;
        #pragma unroll
        for (int dy = 0; dy < 3; ++dy) {
            int yy = y + dy - 1;
            if (yy < 0 || yy > 63) continue;
            const float* row = xp + yy * 64 + x4 * 4;
            f32x4 mm = *(const f32x4*)row;
            float xl = (x4 > 0)  ? row[-1] : 0.f;
            float xr = (x4 < 15) ? row[4]  : 0.f;
            float wa = wrow[ci * 9 + dy * 3 + 0];
            float wb = wrow[ci * 9 + dy * 3 + 1];
            float wc = wrow[ci * 9 + dy * 3 + 2];
            o0 = fmaf(wa, xl,    fmaf(wb, mm[0], fmaf(wc, mm[1], o0)));
            o1 = fmaf(wa, mm[0], fmaf(wb, mm[1], fmaf(wc, mm[2], o1)));
            o2 = fmaf(wa, mm[1], fmaf(wb, mm[2], fmaf(wc, mm[3], o2)));
            o3 = fmaf(wa, mm[2], fmaf(wb, mm[3], fmaf(wc, xr,    o3)));
        }
    }
    f32x4 r = { fmaxf(o0, 0.f), fmaxf(o1, 0.f), fmaxf(o2, 0.f), fmaxf(o3, 0.f) };
    *(f32x4*)&h[flat * 4] = r;
}

// ---------- Kernel B: per-bucket MFMA GEMM, register-streamed W, barrier-free K-loop ----------
__global__ __launch_bounds__(512) void dyn_kernel(
        const float* __restrict__ h, const float* __restrict__ emb,
        const float* __restrict__ w2, const float* __restrict__ b2,
        const float* __restrict__ x, const int* __restrict__ offsets,
        const int* __restrict__ sorted, float* __restrict__ out) {

    __shared__ alignas(16) unsigned short Pl[NPC * PSTR];  // 40960 B patches (bf16, shifted rows)
    __shared__ alignas(16) unsigned short Dl[NPC * 72];    //  4608 B intermediate
    __shared__ alignas(16) unsigned short w2l[64 * 72];    //  9216 B 1x1 weights bf16
    __shared__ int pixs[NPC];

    int t = blockIdx.x;
    int start = offsets[t];
    int n = offsets[t + 1] - start;
    if (n <= 0) return;

    int tid  = threadIdx.x;
    int lane = tid & 63;
    int wv   = tid >> 6;
    int m    = wv & 3;          // M-tile (16 out channels)
    int ph   = wv >> 2;         // pixel half
    int ra   = lane & 15;
    int kg   = lane >> 4;

    const float* Wt = emb + (size_t)t * (64 * ROWLEN);

    // stage w2 -> bf16 LDS (once)
    {
        int o = tid >> 3, i8 = (tid & 7) * 8;
        const float* src = w2 + o * 64 + i8;
        u16x8 v;
        #pragma unroll
        for (int j = 0; j < 8; ++j) v[j] = f2bf(src[j]);
        *(u16x8*)&w2l[o * 72 + i8] = v;
    }

    // per-lane bases
    const float* wl = Wt + (m * 16 + ra) * ROWLEN + kg * 8;     // A-rows, imm-offset loads
    const float* bl = Wt + (m * 16 + kg * 4) * ROWLEN + KD;     // bias rows
    const unsigned short* pB = Pl + (ph * 16 + ra) * PSTR + (ra & 7) * 8 + kg * 8;

    // gather roles
    int gp = tid >> 4;          // pixel 0..31
    int gk = tid & 15;
    unsigned short* pdst = Pl + gp * PSTR + (gp & 7) * 8;

    for (int base = 0; base < n; base += NPC) {
        __syncthreads();   // protect pixs/Pl/Dl from previous iteration's readers
        if (tid < NPC) pixs[tid] = (base + tid < n) ? sorted[start + base + tid] : -1;
        __syncthreads();

        // ---- stage full patch tile P[32 px][576 k] bf16, shifted rows ----
        {
            int pixel = pixs[gp];
            int py = pixel >> 6, px = pixel & 63;
            #pragma unroll
            for (int pass = 0; pass < 9; ++pass) {
                int k0 = pass * 64 + gk * 4;
                u16x4 v;
                #pragma unroll
                for (int j = 0; j < 4; ++j) {
                    int k = k0 + j;
                    int cch = k / 9, r9 = k - cch * 9;
                    int dy = r9 / 3, dx = r9 - dy * 3;
                    float val = 0.f;
                    if (pixel >= 0) {
                        int yy = py + dy - 1, xx = px + dx - 1;
                        if (yy >= 0 && yy < 64 && xx >= 0 && xx < 64)
                            val = h[cch * 4096 + yy * 64 + xx];
                    }
                    v[j] = f2bf(val);
                }
                *(u16x4*)(pdst + k0) = v;
            }
        }
        // bias prefetch (overlaps with barrier)
        float bias0 = bl[0 * ROWLEN], bias1 = bl[1 * ROWLEN];
        float bias2 = bl[2 * ROWLEN], bias3 = bl[3 * ROWLEN];
        __syncthreads();   // P ready (also covers w2l on first iteration)

        // ---- barrier-free K-loop: 9 chunks of 64, depth-2 register prefetch ----
        f32x4 acc = {0.f, 0.f, 0.f, 0.f};
        float A0[16], A1[16], A2[16];

        #define LOADW(D, ck) { _Pragma("unroll") \
            for (int q = 0; q < 16; ++q) D[q] = wl[(ck) * 64 + (q >> 3) * 32 + (q & 7)]; }

        #define CHUNK(D, ck) { _Pragma("unroll") \
            for (int ks = 0; ks < 2; ++ks) { \
                u16x8 av; \
                _Pragma("unroll") \
                for (int j = 0; j < 8; ++j) av[j] = f2bf(D[ks * 8 + j]); \
                u16x8 bv = *(const u16x8*)(pB + (ck) * 64 + ks * 32); \
                acc = __builtin_amdgcn_mfma_f32_16x16x32_bf16( \
                        __builtin_bit_cast(short8, av), \
                        __builtin_bit_cast(short8, bv), acc, 0, 0, 0); } }

        LOADW(A0, 0); LOADW(A1, 1);
        LOADW(A2, 2); CHUNK(A0, 0);
        LOADW(A0, 3); CHUNK(A1, 1);
        LOADW(A1, 4); CHUNK(A2, 2);
        LOADW(A2, 5); CHUNK(A0, 3);
        LOADW(A0, 6); CHUNK(A1, 4);
        LOADW(A1, 7); CHUNK(A2, 5);
        LOADW(A2, 8); CHUNK(A0, 6);
        CHUNK(A1, 7); CHUNK(A2, 8);

        #undef LOADW
        #undef CHUNK

        // ---- bias + relu -> Dl (bf16) ----
        {
            int pi = ph * 16 + ra;
            u16x4 dv;
            dv[0] = f2bf(fmaxf(acc[0] + bias0, 0.f));
            dv[1] = f2bf(fmaxf(acc[1] + bias1, 0.f));
            dv[2] = f2bf(fmaxf(acc[2] + bias2, 0.f));
            dv[3] = f2bf(fmaxf(acc[3] + bias3, 0.f));
            *(u16x4*)&Dl[pi * 72 + m * 16 + kg * 4] = dv;
        }
        __syncthreads();   // D ready

        // ---- GEMM2: 1x1 conv (K=64) ----
        f32x4 acc2 = {0.f, 0.f, 0.f, 0.f};
        #pragma unroll
        for (int ks = 0; ks < 2; ++ks) {
            u16x8 a2  = *(const u16x8*)&w2l[(m * 16 + ra) * 72 + ks * 32 + kg * 8];
            u16x8 b2v = *(const u16x8*)&Dl[(ph * 16 + ra) * 72 + ks * 32 + kg * 8];
            acc2 = __builtin_amdgcn_mfma_f32_16x16x32_bf16(
                       __builtin_bit_cast(short8, a2),
                       __builtin_bit_cast(short8, b2v), acc2, 0, 0, 0);
        }

        // ---- epilogue: + b2 + residual, relu, store ----
        {
            int pi = ph * 16 + ra;
            int pixel = pixs[pi];
            if (pixel >= 0) {
                int o0 = m * 16 + kg * 4;
                #pragma unroll
                for (int j = 0; j < 4; ++j) {
                    int o = o0 + j;
                    float v = acc2[j] + b2[o] + x[o * 4096 + pixel];
                    out[o * 4096 + pixel] = fmaxf(v, 0.f);
                }
            }
        }
    }
}

extern "C" void kernel_launch(void* const* d_in, const int* in_sizes, int n_in,
                              void* d_out, int out_size, void* d_ws, size_t ws_size,
                              hipStream_t stream) {
    const float* x       = (const float*)d_in[0];
    const int*   buckets = (const int*)d_in[1];
    const float* w1      = (const float*)d_in[2];
    const float* b1      = (const float*)d_in[3];
    const float* emb     = (const float*)d_in[4];
    const float* w2      = (const float*)d_in[5];
    const float* b2      = (const float*)d_in[6];
    float* out = (float*)d_out;

    char* ws = (char*)d_ws;
    float* h       = (float*)ws;                       // 1 MB
    int*   offsets = (int*)(ws + (1 << 20));           // 217 ints
    int*   sorted  = (int*)(ws + (1 << 20) + 1024);    // 4096 ints

    body1_sort_kernel<<<257, 256, 0, stream>>>(x, w1, b1, buckets, h, offsets, sorted);
    dyn_kernel<<<NTYPES, 512, 0, stream>>>(h, emb, w2, b2, x, offsets, sorted, out);
}